// Round 10
// baseline (2110.484 us; speedup 1.0000x reference)
//
#include <hip/hip_runtime.h>

typedef unsigned short u16;
typedef float f32x4 __attribute__((ext_vector_type(4)));
typedef short s16x8 __attribute__((ext_vector_type(8)));

#define T_TOK   16448L   // 257*64
#define D_DIM   768L
#define H_DIM   3072L
#define E_NUM   8L
#define M_PAD   16512L   // 129*128 ; halves: A=8192 rows (64 tiles), B=8320 rows (65 tiles)

// ---------- helpers ----------
__device__ __forceinline__ u16 f2bf(float f){
  unsigned u = __float_as_uint(f);
  u = u + 0x7FFFu + ((u >> 16) & 1u);          // RNE
  return (u16)(u >> 16);
}
__device__ __forceinline__ unsigned f2bf2(float a, float b){
  return (unsigned)f2bf(a) | ((unsigned)f2bf(b) << 16);
}

__device__ __forceinline__ void gload_lds16(const u16* g, u16* s){
  __builtin_amdgcn_global_load_lds((const __attribute__((address_space(1))) void*)g,
                                   (__attribute__((address_space(3))) void*)s,
                                   16, 0, 0);
}

// bijective XCD chunking (m204)
__device__ __forceinline__ int xcd_chunk(int idx, int n){
  const int q = n >> 3, r = n & 7, x = idx & 7;
  return (x < r ? x*(q+1) : r*(q+1) + (x-r)*q) + (idx >> 3);
}

// ---------- fp32 -> bf16 (zero-padded tail) ----------
__global__ void k_conv(const float* __restrict__ in, u16* __restrict__ outp,
                       long nValid, long nTotal){
  long i = (long)blockIdx.x * blockDim.x + threadIdx.x;
  long stride = (long)gridDim.x * blockDim.x;
  long n8 = nTotal >> 3;
  for (long v = i; v < n8; v += stride){
    long base = v << 3;
    uint4 o;
    if (base < nValid){
      const float4 f0 = *(const float4*)(in + base);
      const float4 f1 = *(const float4*)(in + base + 4);
      o.x = f2bf2(f0.x, f0.y); o.y = f2bf2(f0.z, f0.w);
      o.z = f2bf2(f1.x, f1.y); o.w = f2bf2(f1.z, f1.w);
    } else {
      o.x = 0u; o.y = 0u; o.z = 0u; o.w = 0u;
    }
    *(uint4*)(outp + base) = o;
  }
}

// ---------- router: logits + softmax (fp32, one wave per token) ----------
__global__ void k_router(const float* __restrict__ x, const float* __restrict__ Wr,
                         const float* __restrict__ br, float* __restrict__ probs){
  int w = (int)((blockIdx.x * (long)blockDim.x + threadIdx.x) >> 6);
  int lane = threadIdx.x & 63;
  if (w >= (int)T_TOK) return;
  const float* xr = x + (long)w * D_DIM;
  float l[8];
#pragma unroll
  for (int e = 0; e < 8; ++e) l[e] = 0.f;
#pragma unroll
  for (int c = 0; c < 3; ++c){
    const float4 xv = *(const float4*)(xr + c*256 + lane*4);
#pragma unroll
    for (int e = 0; e < 8; ++e){
      const float4 wv = *(const float4*)(Wr + (long)e*D_DIM + c*256 + lane*4);
      l[e] += xv.x*wv.x + xv.y*wv.y + xv.z*wv.z + xv.w*wv.w;
    }
  }
#pragma unroll
  for (int e = 0; e < 8; ++e){
#pragma unroll
    for (int off = 32; off > 0; off >>= 1) l[e] += __shfl_xor(l[e], off);
    l[e] += br[e];
  }
  float m = l[0];
#pragma unroll
  for (int e = 1; e < 8; ++e) m = fmaxf(m, l[e]);
  float s = 0.f;
#pragma unroll
  for (int e = 0; e < 8; ++e){ l[e] = __expf(l[e] - m); s += l[e]; }
  float inv = 1.f / s;
  if (lane == 0){
    float4 p0 = { l[0]*inv, l[1]*inv, l[2]*inv, l[3]*inv };
    float4 p1 = { l[4]*inv, l[5]*inv, l[6]*inv, l[7]*inv };
    *(float4*)(probs + (long)w*8)     = p0;
    *(float4*)(probs + (long)w*8 + 4) = p1;
  }
}

// ---------- 128x128 GEMM body (m97 structure): single 32 KB buffer, 2 barriers/tile,
// 4 waves, BK=64, hoisted addressing. All latency hiding via 4-5 blocks/CU TLP. ----------
// LDS[r][p] = Gsrc[r][p ^ (r&7)] (pre-swizzled source chunk, lane-linear dest);
// readers apply the same involution. Proven conflict-free (r3/r6).
__device__ __forceinline__ void gemm128(const u16* __restrict__ Ag, long lda,
                                        const u16* __restrict__ Bg, long ldb,
                                        int NT, u16* As, u16* Bs,
                                        int tid, f32x4 (&acc)[4][4]){
  const int l  = tid & 63, w = tid >> 6;
  const int wr = w >> 1,  wc = w & 1;
  const int g4 = l >> 4,  ln = l & 15;

  // hoisted staging pointers: advance by 64 elems (128 B) per K-tile
  const int rw = l >> 3;
  const int c8 = (l & 7) ^ rw;
  const u16* pA = Ag + (long)(w*8 + rw) * lda + c8*8;
  const u16* pB = Bg + (long)(w*8 + rw) * ldb + c8*8;
  const long sA = 32 * lda, sB = 32 * ldb;     // 32-row strides (uniform -> SGPR)
  u16* dA = As + w*512;
  u16* dB = Bs + w*512;

  // hoisted ds_read element offsets
  int offA[2][4], offB[2][4];
#pragma unroll
  for (int kk = 0; kk < 2; ++kk)
#pragma unroll
    for (int i = 0; i < 4; ++i){
      const int co = (((kk<<2) | g4) ^ (ln & 7)) << 3;
      offA[kk][i] = (wr*64 + i*16 + ln)*64 + co;
      offB[kk][i] = (wc*64 + i*16 + ln)*64 + co;
    }

  for (int kt = 0; kt < NT; ++kt){
    // stage tile kt (single buffer; __syncthreads drains vmcnt)
    gload_lds16(pA,        dA);
    gload_lds16(pA +   sA, dA + 2048);
    gload_lds16(pA + 2*sA, dA + 4096);
    gload_lds16(pA + 3*sA, dA + 6144);
    gload_lds16(pB,        dB);
    gload_lds16(pB +   sB, dB + 2048);
    gload_lds16(pB + 2*sB, dB + 4096);
    gload_lds16(pB + 3*sB, dB + 6144);
    pA += 64; pB += 64;
    __syncthreads();

    // one unbroken compiler-scheduled body: 16 ds_read_b128 + 32 MFMA
    s16x8 a0[4], b0[4], a1[4], b1[4];
#pragma unroll
    for (int i = 0; i < 4; ++i) a0[i] = *(const s16x8*)(As + offA[0][i]);
#pragma unroll
    for (int i = 0; i < 4; ++i) b0[i] = *(const s16x8*)(Bs + offB[0][i]);
#pragma unroll
    for (int mi = 0; mi < 4; ++mi)
#pragma unroll
      for (int ni = 0; ni < 4; ++ni)
        acc[mi][ni] = __builtin_amdgcn_mfma_f32_16x16x32_bf16(a0[mi], b0[ni], acc[mi][ni], 0, 0, 0);
#pragma unroll
    for (int i = 0; i < 4; ++i) a1[i] = *(const s16x8*)(As + offA[1][i]);
#pragma unroll
    for (int i = 0; i < 4; ++i) b1[i] = *(const s16x8*)(Bs + offB[1][i]);
#pragma unroll
    for (int mi = 0; mi < 4; ++mi)
#pragma unroll
      for (int ni = 0; ni < 4; ++ni)
        acc[mi][ni] = __builtin_amdgcn_mfma_f32_16x16x32_bf16(a1[mi], b1[ni], acc[mi][ni], 0, 0, 0);
    __syncthreads();
  }
}

// ---------- paired dispatch: gemm2(e2, one token-half) + gemm1(e1, other half) ----------
__global__ __launch_bounds__(256) void k_pair(const u16* __restrict__ xb,
                                              const u16* __restrict__ w1b,
                                              const float* __restrict__ b1,
                                              const u16* __restrict__ w2b,
                                              const float* __restrict__ b2,
                                              const float* __restrict__ probs,
                                              float* __restrict__ out,
                                              const u16* __restrict__ hbR,
                                              u16* __restrict__ hbW,
                                              int e2, int t02,
                                              int e1, int t01, int mt1, int n2){
  __shared__ alignas(16) u16 As[8192];
  __shared__ alignas(16) u16 Bs[8192];
  const int tid = threadIdx.x;
  const int l  = tid & 63, w = tid >> 6;
  const int wr = w >> 1,  wc = w & 1;
  const int g4 = l >> 4,  ln = l & 15;
  const int bx = (int)blockIdx.x;
  f32x4 acc[4][4] = {};

  if (bx < n2){
    // ---- gemm2: XCD-chunked, y-fastest (6 N-tiles share the A-panel) ----
    const int wg = xcd_chunk(bx, n2);
    const int tx = wg / 6, ty = wg % 6;
    const int m0 = tx << 7, n0 = ty << 7;
    gemm128(hbR + (long)m0 * H_DIM, H_DIM,
            w2b + ((long)e2 * D_DIM + n0) * H_DIM, H_DIM,
            48, As, Bs, tid, acc);
    float bias[4];
#pragma unroll
    for (int ni = 0; ni < 4; ++ni) bias[ni] = b2[(long)e2*D_DIM + n0 + wc*64 + ni*16 + ln];
#pragma unroll
    for (int mi = 0; mi < 4; ++mi){
#pragma unroll
      for (int j = 0; j < 4; ++j){
        const int gt = t02 + m0 + wr*64 + mi*16 + g4*4 + j;
        if (gt < (int)T_TOK){
          const float p = probs[(long)gt*8 + e2];
          float* dst = out + (long)gt * D_DIM + n0 + wc*64;
#pragma unroll
          for (int ni = 0; ni < 4; ++ni){
            const float v = p * (acc[mi][ni][j] + bias[ni]);
            if (e2 == 0) dst[ni*16 + ln] = v;
            else         dst[ni*16 + ln] += v;
          }
        }
      }
    }
  } else {
    // ---- gemm1: XCD-chunked, x-fastest (B-panel reused along chunk) ----
    const int n1 = (int)gridDim.x - n2;
    const int wg = xcd_chunk(bx - n2, n1);
    const int tx = wg % mt1, ty = wg / mt1;
    const int m0 = tx << 7, n0 = ty << 7;
    gemm128(xb + (long)(t01 + m0) * D_DIM, D_DIM,
            w1b + ((long)e1 * H_DIM + n0) * D_DIM, D_DIM,
            12, As, Bs, tid, acc);
    float bias[4];
#pragma unroll
    for (int ni = 0; ni < 4; ++ni) bias[ni] = b1[(long)e1*H_DIM + n0 + wc*64 + ni*16 + ln];
#pragma unroll
    for (int mi = 0; mi < 4; ++mi){
#pragma unroll
      for (int j = 0; j < 4; ++j){
        const int r = m0 + wr*64 + mi*16 + g4*4 + j;      // half-local row
        u16* dst = hbW + (long)r * H_DIM + n0 + wc*64;
#pragma unroll
        for (int ni = 0; ni < 4; ++ni){
          const float v  = acc[mi][ni][j] + bias[ni];
          const float gl = v / (1.0f + __expf(-1.702f * v));  // quick_gelu
          dst[ni*16 + ln] = f2bf(gl);
        }
      }
    }
  }
}

// ---------- host ----------
extern "C" void kernel_launch(void* const* d_in, const int* in_sizes, int n_in,
                              void* d_out, int out_size, void* d_ws, size_t ws_size,
                              hipStream_t stream){
  const float* x  = (const float*)d_in[0];
  const float* W1 = (const float*)d_in[1];
  const float* b1 = (const float*)d_in[2];
  const float* W2 = (const float*)d_in[3];
  const float* b2 = (const float*)d_in[4];
  const float* Wr = (const float*)d_in[5];
  const float* br = (const float*)d_in[6];
  float* out = (float*)d_out;

  char* ws = (char*)d_ws;
  size_t off = 0;
  auto carve = [&](size_t bytes)->void*{
    void* p = ws + off; off += (bytes + 255) & ~(size_t)255; return p;
  };
  u16*   xb    = (u16*)  carve((size_t)M_PAD * D_DIM * 2);
  u16*   w1b   = (u16*)  carve((size_t)E_NUM * H_DIM * D_DIM * 2);
  u16*   w2b   = (u16*)  carve((size_t)E_NUM * D_DIM * H_DIM * 2);
  float* probs = (float*)carve((size_t)T_TOK * E_NUM * 4);
  u16*   hbA   = (u16*)  carve((size_t)8192 * H_DIM * 2);   // tokens [0, 8192)
  u16*   hbB   = (u16*)  carve((size_t)8320 * H_DIM * 2);   // tokens [8192, 16512)

  // conversions + router
  k_conv<<<dim3(2048), dim3(256), 0, stream>>>(x,  xb,  T_TOK*D_DIM, M_PAD*D_DIM);
  k_conv<<<dim3(2048), dim3(256), 0, stream>>>(W1, w1b, E_NUM*H_DIM*D_DIM, E_NUM*H_DIM*D_DIM);
  k_conv<<<dim3(2048), dim3(256), 0, stream>>>(W2, w2b, E_NUM*D_DIM*H_DIM, E_NUM*D_DIM*H_DIM);
  k_router<<<dim3(4112), dim3(256), 0, stream>>>(x, Wr, br, probs);

  const int MTA = 64, MTB = 65;      // 128-row tile counts per token-half
  const int T0A = 0,  T0B = 8192;

  auto pair = [&](int e2, const u16* hbR, int t02, int mt2,
                  int e1, u16* hbW, int t01, int mt1){
    const int n2 = mt2 * 6, n1 = mt1 * 24;
    k_pair<<<dim3((unsigned)(n2 + n1)), dim3(256), 0, stream>>>(
        xb, w1b, b1, w2b, b2, probs, out, hbR, hbW,
        e2, t02, e1, t01, mt1, n2);
  };

  // ping-pong: D0: g1(0,A); D(2e+1): g2(e,A)+g1(e,B); D(2e+2): g2(e,B)+g1(e+1,A); D16: g2(7,B)
  pair(0, nullptr, 0, 0, 0, hbA, T0A, MTA);
  for (int e = 0; e < 8; ++e){
    pair(e, hbA, T0A, MTA, e, hbB, T0B, MTB);
    if (e < 7) pair(e, hbB, T0B, MTB, e + 1, hbA, T0A, MTA);
  }
  pair(7, hbB, T0B, MTB, 0, nullptr, 0, 0);
}